// Round 11
// baseline (1143.361 us; speedup 1.0000x reference)
//
#include <hip/hip_runtime.h>
#include <math.h>

#define NROWS 131072
#define DIN   16
#define DC    16
#define UNITS 512
#define BINS  10
#define DT    8
#define FOUT  248
#define M_TILE 64               // rows per workgroup
#define NWG   (NROWS / M_TILE)  // 2048

// d_ws byte offsets
#define Z_OFF    0u
#define W0F_OFF  8388608u   // [8][32 ut][512]           fp16, 16x16 fragment-major
#define W1F_OFF  8650752u   // [8][16 ut32][32 ks][512]  fp16, 32x32 fragment-major
#define W2F_OFF  12845056u  // [8][8 ut232][32 kk][512]  fp16, 32x32 fragment-major

typedef _Float16 h16x8 __attribute__((ext_vector_type(8)));
typedef float    f32x4 __attribute__((ext_vector_type(4)));
typedef float    f32x16 __attribute__((ext_vector_type(16)));

union Frag { h16x8 v; uint4 q; unsigned int u32[4]; _Float16 h[8]; };

// RNE fp32->fp16 pack (NOT cvt_pkrtz: RTZ's systematic truncation bias on
// all-positive post-ReLU activations doubled the end-to-end absmax error)
static __device__ inline unsigned int pack2h(float lo, float hi) {
    union { _Float16 h[2]; unsigned int u; } x;
    x.h[0] = (_Float16)lo; x.h[1] = (_Float16)hi;
    return x.u;
}

static __device__ inline float fast_rcp(float x) { return __builtin_amdgcn_rcpf(x); }

// ---------------- weight convert prologue ----------------
// 16x16 A-frag (W0F): lane = quad*16+l15; elem j -> (m = ut*16+l15, k = quad*8+j)
// 32x32 A-frag (W1F/W2F): lane l; elem j -> (m = ut32*32+(l&31), k = ks*16+(l>>5)*8+j)
__global__ __launch_bounds__(256)
void prep_weights(const float* __restrict__ W0, const float* __restrict__ W1,
                  const float* __restrict__ W2, _Float16* __restrict__ W0F,
                  _Float16* __restrict__ W1F, _Float16* __restrict__ W2F)
{
    const int idx = blockIdx.x * 256 + threadIdx.x;
    const int SZ0 = 8 * 32 * 512;           // 131072
    const int SZ1 = 8 * 16 * 32 * 512;      // 2097152
    const int SZ2 = 8 * 8 * 32 * 512;       // 1048576
    if (idx < SZ0) {
        int b = idx >> 14, r = idx & 16383;
        int ut = r >> 9, le = r & 511;
        int lane = le >> 3, j = le & 7;
        int quad = lane >> 4, l15 = lane & 15;
        int m = ut * 16 + l15, k = quad * 8 + j;
        W0F[idx] = (k < 24) ? (_Float16)W0[b * (24 * 512) + k * 512 + m] : (_Float16)0.f;
    } else if (idx < SZ0 + SZ1) {
        int i = idx - SZ0;
        int b = i >> 18, r = i & 262143;
        int ut32 = r >> 14, r2 = r & 16383;
        int ks = r2 >> 9, le = r2 & 511;
        int lane = le >> 3, j = le & 7;
        int m = ut32 * 32 + (lane & 31);
        int k = ks * 16 + (lane >> 5) * 8 + j;
        W1F[i] = (_Float16)W1[(b << 18) + k * 512 + m];
    } else if (idx < SZ0 + SZ1 + SZ2) {
        int i = idx - SZ0 - SZ1;
        int b = i >> 17, r = i & 131071;
        int ut232 = r >> 14, r2 = r & 16383;
        int kk = r2 >> 9, le = r2 & 511;
        int lane = le >> 3, j = le & 7;
        int m2 = ut232 * 32 + (lane & 31);
        int k = kk * 16 + (lane >> 5) * 8 + j;
        W2F[i] = (m2 < FOUT) ? (_Float16)W2[b * (512 * FOUT) + k * FOUT + m2] : (_Float16)0.f;
    }
}

// ---------------- fused coupling block (split-dispatch structure) ----------------
// One dispatch per coupling block: all 2048 WGs share one block's ~0.8 MB weight
// set -> L2-hot by construction (R4/R5 fusions thrashed L2).
// GEMM1 stays 16x16x32 (tiny). GEMM2/3 reshaped to 32x32x16: halves MFMA
// instruction count (384 -> 192) and gains +17% matrix-pipe FLOP/cyc (m119).
// LDS byte layout for H0/H1 unchanged: [row n][unit-chunk (u>>3) ^ (n&7)] —
// a 32-wide B-frag reads 8 consecutive units = one 16B chunk per lane.
// Waves: GEMM2: ut32 {2w,2w+1} x rt32 {0,1}. GEMM3: ut232 = w x rt32 {0,1}.
__global__ __launch_bounds__(512, 4)
void flow_block_kernel(const float* __restrict__ z, const float* __restrict__ c,
                       const _Float16* __restrict__ W0F, const float* __restrict__ b0,
                       const _Float16* __restrict__ W1F, const float* __restrict__ b1,
                       const _Float16* __restrict__ W2F, const float* __restrict__ b2,
                       float* __restrict__ zout, float* __restrict__ logdet,
                       int p, int inv)
{
    __shared__ __align__(16) char smem[65536];

    const int t    = threadIdx.x;
    const int wave = t >> 6;
    const int lane = t & 63;
    const int quad = lane >> 4;
    const int l15  = lane & 15;
    const int l31  = lane & 31;
    const int half = lane >> 5;
    const int row0 = blockIdx.x * M_TILE;
    const int lowmask = (1 << p) - 1;
    const int cv = 1 - inv, tv = inv;
    const int lofs = lane * 8;          // element offset of this lane's frag

    // ---- GEMM1 B-frags: X^T = [z_cond | c | 0pad], one per row-tile ----
    Frag bx[4];
    #pragma unroll
    for (int rt = 0; rt < 4; ++rt) {
        const int n = rt * 16 + l15;
        const float* zr = z + (size_t)(row0 + n) * DIN;
        const float* cr = c + (size_t)(row0 + n) * DC;
        float v[8];
        if (quad == 0) {
            #pragma unroll
            for (int j = 0; j < 8; ++j) {
                const int col = ((j >> p) << (p + 1)) | (cv << p) | (j & lowmask);
                v[j] = zr[col];
            }
        } else if (quad == 1) {
            #pragma unroll
            for (int j = 0; j < 8; ++j) v[j] = cr[j];
        } else if (quad == 2) {
            #pragma unroll
            for (int j = 0; j < 8; ++j) v[j] = cr[8 + j];
        } else {
            #pragma unroll
            for (int j = 0; j < 8; ++j) v[j] = 0.f;
        }
        #pragma unroll
        for (int j = 0; j < 4; ++j) bx[rt].u32[j] = pack2h(v[2 * j], v[2 * j + 1]);
    }

    // ---- GEMM1 (16x16x32): H0^T = relu(W0F @ X^T + b0) -> swizzled LDS ----
    #pragma unroll
    for (int j = 0; j < 4; ++j) {
        const int ut = wave * 4 + j;
        Frag a; a.q = *(const uint4*)(W0F + (ut << 9) + lofs);
        const f32x4 bias = *(const f32x4*)(b0 + ut * 16 + quad * 4);
        const int m0 = ut * 16 + quad * 4;
        #pragma unroll
        for (int rt = 0; rt < 4; ++rt) {
            f32x4 acc = __builtin_amdgcn_mfma_f32_16x16x32_f16(a.v, bx[rt].v, bias, 0, 0, 0);
            const int n = rt * 16 + l15;
            uint2 w2;
            w2.x = pack2h(fmaxf(acc.x, 0.f), fmaxf(acc.y, 0.f));
            w2.y = pack2h(fmaxf(acc.z, 0.f), fmaxf(acc.w, 0.f));
            const int addr = n * 1024 + (((m0 >> 3) ^ (n & 7)) * 16) + ((m0 & 4) * 2);
            *(uint2*)(smem + addr) = w2;
        }
    }
    __syncthreads();

    // ---- GEMM2 (32x32x16): H1 = relu(H0 @ W1 + b1), kept in registers ----
    // C/D layout: col = lane&31 (row n), row = (reg&3)+8*(reg>>2)+4*half (unit)
    f32x16 h1a[2][2];   // [i ut32][rt32]
    #pragma unroll
    for (int i = 0; i < 2; ++i) {
        const int base = (wave * 2 + i) * 32;
        #pragma unroll
        for (int g = 0; g < 4; ++g) {
            const f32x4 bb = *(const f32x4*)(b1 + base + 8 * g + 4 * half);
            #pragma unroll
            for (int rt = 0; rt < 2; ++rt) {
                h1a[i][rt][4 * g + 0] = bb.x; h1a[i][rt][4 * g + 1] = bb.y;
                h1a[i][rt][4 * g + 2] = bb.z; h1a[i][rt][4 * g + 3] = bb.w;
            }
        }
    }
    #pragma unroll 4
    for (int ks = 0; ks < 32; ++ks) {
        Frag B[2];
        #pragma unroll
        for (int rt = 0; rt < 2; ++rt) {
            const int n = rt * 32 + l31;
            B[rt].v = *(const h16x8*)(smem + n * 1024 + (((ks * 2 + half) ^ (n & 7)) * 16));
        }
        __builtin_amdgcn_s_setprio(1);
        #pragma unroll
        for (int i = 0; i < 2; ++i) {
            Frag a; a.q = *(const uint4*)(W1F + ((((wave * 2 + i) * 32) + ks) << 9) + lofs);
            #pragma unroll
            for (int rt = 0; rt < 2; ++rt)
                h1a[i][rt] = __builtin_amdgcn_mfma_f32_32x32x16_f16(a.v, B[rt].v, h1a[i][rt], 0, 0, 0);
        }
        __builtin_amdgcn_s_setprio(0);
    }
    __syncthreads();   // everyone done reading H0

    // ---- stage full H1 (relu, fp16) into the same swizzled LDS layout ----
    // regs 4g..4g+3 -> units m..m+3 with m = ut32*32 + 8g + 4*half
    #pragma unroll
    for (int i = 0; i < 2; ++i) {
        #pragma unroll
        for (int rt = 0; rt < 2; ++rt) {
            const int n = rt * 32 + l31;
            #pragma unroll
            for (int g = 0; g < 4; ++g) {
                const int m = (wave * 2 + i) * 32 + 8 * g + 4 * half;
                uint2 w2;
                w2.x = pack2h(fmaxf(h1a[i][rt][4 * g + 0], 0.f), fmaxf(h1a[i][rt][4 * g + 1], 0.f));
                w2.y = pack2h(fmaxf(h1a[i][rt][4 * g + 2], 0.f), fmaxf(h1a[i][rt][4 * g + 3], 0.f));
                const int addr = n * 1024 + (((m >> 3) ^ (n & 7)) * 16) + ((m & 4) * 2);
                *(uint2*)(smem + addr) = w2;
            }
        }
    }
    __syncthreads();

    // ---- GEMM3 (32x32x16): P = H1 @ W2 + b2 ----
    f32x16 pa[2];       // [rt32]; ut232 = wave
    #pragma unroll
    for (int g = 0; g < 4; ++g) {
        const int m2 = wave * 32 + 8 * g + 4 * half;
        f32x4 bb;
        if (m2 < FOUT) bb = *(const f32x4*)(b2 + m2);
        else { bb.x = 0.f; bb.y = 0.f; bb.z = 0.f; bb.w = 0.f; }
        #pragma unroll
        for (int rt = 0; rt < 2; ++rt) {
            pa[rt][4 * g + 0] = bb.x; pa[rt][4 * g + 1] = bb.y;
            pa[rt][4 * g + 2] = bb.z; pa[rt][4 * g + 3] = bb.w;
        }
    }
    #pragma unroll 4
    for (int kk = 0; kk < 32; ++kk) {
        Frag B[2];
        #pragma unroll
        for (int rt = 0; rt < 2; ++rt) {
            const int n = rt * 32 + l31;
            B[rt].v = *(const h16x8*)(smem + n * 1024 + (((kk * 2 + half) ^ (n & 7)) * 16));
        }
        __builtin_amdgcn_s_setprio(1);
        {
            Frag a; a.q = *(const uint4*)(W2F + (((wave * 32) + kk) << 9) + lofs);
            #pragma unroll
            for (int rt = 0; rt < 2; ++rt)
                pa[rt] = __builtin_amdgcn_mfma_f32_32x32x16_f16(a.v, B[rt].v, pa[rt], 0, 0, 0);
        }
        __builtin_amdgcn_s_setprio(0);
    }
    __syncthreads();   // H1 reads done; reuse LDS for fp32 P

    // ---- dump P (fp32) to LDS for the spline phase: [64 rows][252] ----
    #pragma unroll
    for (int rt = 0; rt < 2; ++rt) {
        const int n = rt * 32 + l31;
        #pragma unroll
        for (int g = 0; g < 4; ++g) {
            const int m2 = wave * 32 + 8 * g + 4 * half;
            if (m2 < FOUT) {
                f32x4 o;
                o.x = pa[rt][4 * g + 0]; o.y = pa[rt][4 * g + 1];
                o.z = pa[rt][4 * g + 2]; o.w = pa[rt][4 * g + 3];
                *(f32x4*)(smem + n * 1008 + m2 * 4) = o;
            }
        }
    }
    __syncthreads();

    // ---- RQS spline: thread t -> (row r = t>>3, dim d = t&7) ----
    // Native transcendentals; fused logdet log; cndmask bin-select; lazy softplus.
    {
        const int r = t >> 3;
        const int d = t & 7;
        const int row = row0 + r;
        const int td = ((d >> p) << (p + 1)) | (tv << p) | (d & lowmask);

        // issue the scattered x load early to hide latency under the LDS reads
        const float x = z[(size_t)row * DIN + td];

        const float* pp = (const float*)(smem + r * 1008) + d * 31;
        float pv[31];
        #pragma unroll
        for (int i = 0; i < 31; ++i) pv[i] = pp[i];

        float mw = pv[0];
        #pragma unroll
        for (int i = 1; i < BINS; ++i) mw = fmaxf(mw, pv[i]);
        float w[BINS]; float sw = 0.f;
        #pragma unroll
        for (int i = 0; i < BINS; ++i) { w[i] = __expf(pv[i] - mw); sw += w[i]; }
        const float rw = (1.0f - 0.001f * BINS) * fast_rcp(sw);
        #pragma unroll
        for (int i = 0; i < BINS; ++i) w[i] = 0.001f + rw * w[i];

        float mh = pv[BINS];
        #pragma unroll
        for (int i = 1; i < BINS; ++i) mh = fmaxf(mh, pv[BINS + i]);
        float hh[BINS]; float sh = 0.f;
        #pragma unroll
        for (int i = 0; i < BINS; ++i) { hh[i] = __expf(pv[BINS + i] - mh); sh += hh[i]; }
        const float rh = (1.0f - 0.001f * BINS) * fast_rcp(sh);
        #pragma unroll
        for (int i = 0; i < BINS; ++i) hh[i] = 0.001f + rh * hh[i];

        float cw[BINS], ch[BINS];
        cw[0] = 0.f; ch[0] = 0.f;
        #pragma unroll
        for (int i = 0; i < BINS - 1; ++i) { cw[i + 1] = cw[i] + w[i]; ch[i + 1] = ch[i] + hh[i]; }

        // bin select: largest i in [0, BINS-1] with x >= cw[i]
        // (selects RAW derivative params uk, uk1; softplus applied after)
        float xk = cw[0], wk = w[0], yk = ch[0], hk = hh[0];
        float uk = pv[2 * BINS], uk1 = pv[2 * BINS + 1];
        #pragma unroll
        for (int i = 1; i < BINS; ++i) {
            const bool sel = (x >= cw[i]);
            xk  = sel ? cw[i]            : xk;
            wk  = sel ? w[i]             : wk;
            yk  = sel ? ch[i]            : yk;
            hk  = sel ? hh[i]            : hk;
            uk  = sel ? pv[2 * BINS + i]     : uk;
            uk1 = sel ? pv[2 * BINS + i + 1] : uk1;
        }
        const float dk  = 0.001f + fmaxf(uk, 0.f)  + __logf(1.f + __expf(-fabsf(uk)));
        const float dk1 = 0.001f + fmaxf(uk1, 0.f) + __logf(1.f + __expf(-fabsf(uk1)));

        const float inv_wk = fast_rcp(wk);
        float th = (x - xk) * inv_wk;
        th = fminf(fmaxf(th, 0.f), 1.f);
        const float s   = hk * inv_wk;
        const float t1  = th * (1.f - th);
        const float den = s + (dk1 + dk - 2.f * s) * t1;
        const float inv_den = fast_rcp(den);
        const float num = s * th * th + dk * t1;
        const float y   = yk + hk * num * inv_den;
        const float om  = 1.f - th;
        const float r1  = s * inv_den;                 // bounded: s/den <= ~2
        const float q   = r1 * r1 * (dk1 * th * th + 2.f * s * t1 + dk * om * om);
        float ljv = __logf(q);                          // == 2log(s)+log(num2)-2log(den)

        zout[(size_t)row * DIN + td] = y;

        float v = ljv;
        v += __shfl_down(v, 4, 8);
        v += __shfl_down(v, 2, 8);
        v += __shfl_down(v, 1, 8);
        if ((t & 7) == 0) logdet[row0 + (t >> 3)] += v;
    }
}

extern "C" void kernel_launch(void* const* d_in, const int* in_sizes, int n_in,
                              void* d_out, int out_size, void* d_ws, size_t ws_size,
                              hipStream_t stream) {
    (void)in_sizes; (void)n_in; (void)out_size; (void)ws_size;
    const float* x  = (const float*)d_in[0];
    const float* c  = (const float*)d_in[1];
    const float* W0 = (const float*)d_in[2];
    const float* b0 = (const float*)d_in[3];
    const float* W1 = (const float*)d_in[4];
    const float* b1 = (const float*)d_in[5];
    const float* W2 = (const float*)d_in[6];
    const float* b2 = (const float*)d_in[7];
    float* out = (float*)d_out;

    char* ws = (char*)d_ws;
    float* z = (float*)(ws + Z_OFF);
    _Float16* W0F = (_Float16*)(ws + W0F_OFF);
    _Float16* W1F = (_Float16*)(ws + W1F_OFF);
    _Float16* W2F = (_Float16*)(ws + W2F_OFF);

    hipMemcpyAsync(z, x, (size_t)NROWS * DIN * sizeof(float),
                   hipMemcpyDeviceToDevice, stream);
    hipMemsetAsync(out, 0, (size_t)NROWS * sizeof(float), stream);

    prep_weights<<<12800, 256, 0, stream>>>(W0, W1, W2, W0F, W1F, W2F);

    dim3 grid(NWG), block(512);
    for (int b = 0; b < 8; ++b) {
        const int p = b >> 1, inv = b & 1;
        flow_block_kernel<<<grid, block, 0, stream>>>(
            z, c,
            W0F + (size_t)b * 32 * 512,          b0 + (size_t)b * UNITS,
            W1F + (size_t)b * 16 * 32 * 512,     b1 + (size_t)b * UNITS,
            W2F + (size_t)b * 8 * 32 * 512,      b2 + (size_t)b * FOUT,
            z, out, p, inv);
    }
}

// Round 12
// 1009.541 us; speedup vs baseline: 1.1326x; 1.1326x over previous
//
#include <hip/hip_runtime.h>
#include <math.h>

#define NROWS 131072
#define DIN   16
#define DC    16
#define UNITS 512
#define BINS  10
#define DT    8
#define FOUT  248
#define M_TILE 64               // rows per workgroup
#define NWG   (NROWS / M_TILE)  // 2048

// d_ws byte offsets
#define Z_OFF    0u
#define W0F_OFF  8388608u   // [8][32 ut][512]          fp16, fragment-major
#define W1F_OFF  8650752u   // [8][32 ut][16 ks][512]   fp16, fragment-major
#define W2F_OFF  12845056u  // [8][16 ut2][4 c2][4 ks2][512] fp16, fragment-major

typedef _Float16 h16x8 __attribute__((ext_vector_type(8)));
typedef float    f32x4 __attribute__((ext_vector_type(4)));

union Frag { h16x8 v; uint4 q; unsigned int u32[4]; _Float16 h[8]; };

// RNE fp32->fp16 pack (NOT cvt_pkrtz: RTZ's systematic truncation bias on
// all-positive post-ReLU activations doubled the end-to-end absmax error)
static __device__ inline unsigned int pack2h(float lo, float hi) {
    union { _Float16 h[2]; unsigned int u; } x;
    x.h[0] = (_Float16)lo; x.h[1] = (_Float16)hi;
    return x.u;
}

static __device__ inline float fast_rcp(float x) { return __builtin_amdgcn_rcpf(x); }

// ---------------- weight convert prologue: fragment-major layouts ----------------
// lane = quad*16 + l15.  A-frag element j of lane -> weight (m, k):
//   m = ut*16 + l15,  k = kbase + quad*8 + j
__global__ __launch_bounds__(256)
void prep_weights(const float* __restrict__ W0, const float* __restrict__ W1,
                  const float* __restrict__ W2, _Float16* __restrict__ W0F,
                  _Float16* __restrict__ W1F, _Float16* __restrict__ W2F)
{
    const int idx = blockIdx.x * 256 + threadIdx.x;
    const int SZ0 = 8 * 32 * 512;           // 131072
    const int SZ1 = 8 * 32 * 16 * 512;      // 2097152
    const int SZ2 = 8 * 16 * 4 * 4 * 512;   // 1048576
    if (idx < SZ0) {
        int b = idx >> 14, r = idx & 16383;
        int ut = r >> 9, le = r & 511;
        int lane = le >> 3, j = le & 7;
        int quad = lane >> 4, l15 = lane & 15;
        int m = ut * 16 + l15, k = quad * 8 + j;
        W0F[idx] = (k < 24) ? (_Float16)W0[b * (24 * 512) + k * 512 + m] : (_Float16)0.f;
    } else if (idx < SZ0 + SZ1) {
        int i = idx - SZ0;
        int b = i >> 18, r = i & 262143;
        int ut = r >> 13, r2 = r & 8191;
        int ks = r2 >> 9, le = r2 & 511;
        int lane = le >> 3, j = le & 7;
        int quad = lane >> 4, l15 = lane & 15;
        int m = ut * 16 + l15, k = ks * 32 + quad * 8 + j;
        W1F[i] = (_Float16)W1[(b << 18) + k * 512 + m];
    } else if (idx < SZ0 + SZ1 + SZ2) {
        int i = idx - SZ0 - SZ1;
        int b = i >> 17, r = i & 131071;
        int ut2 = r >> 13, r2 = r & 8191;
        int c2 = r2 >> 11, r3 = r2 & 2047;
        int ks2 = r3 >> 9, le = r3 & 511;
        int lane = le >> 3, j = le & 7;
        int quad = lane >> 4, l15 = lane & 15;
        int m = ut2 * 16 + l15, k = c2 * 128 + ks2 * 32 + quad * 8 + j;
        W2F[i] = (m < FOUT) ? (_Float16)W2[b * (512 * FOUT) + k * FOUT + m] : (_Float16)0.f;
    }
}

// ---------------- fused coupling block (split-dispatch structure) ----------------
// One dispatch per coupling block: all 2048 WGs share one block's ~0.8 MB weight
// set -> L2-hot by construction (R4/R5 fusions thrashed L2: FETCH 94 MB -> 666 MB
// -> 1.13 GB). 16x16x32 MFMA: 16 independent accumulators/wave keeps the matrix
// pipe streaming (R11's 32x32x16 reshape had only 4 chains -> latency-bound,
// -18%). R8's register pipeline spilled. VGPR 56 schedule is the verified
// optimum. Waves: GEMM1/2: uts {4w..4w+3} x row-tiles {0..3}.
// GEMM3: ut2 {2w, 2w+1} x row-tiles {0..3}.
__global__ __launch_bounds__(512, 4)
void flow_block_kernel(const float* __restrict__ z, const float* __restrict__ c,
                       const _Float16* __restrict__ W0F, const float* __restrict__ b0,
                       const _Float16* __restrict__ W1F, const float* __restrict__ b1,
                       const _Float16* __restrict__ W2F, const float* __restrict__ b2,
                       float* __restrict__ zout, float* __restrict__ logdet,
                       int p, int inv)
{
    __shared__ __align__(16) char smem[65536];

    const int t    = threadIdx.x;
    const int wave = t >> 6;
    const int lane = t & 63;
    const int quad = lane >> 4;
    const int l15  = lane & 15;
    const int row0 = blockIdx.x * M_TILE;
    const int lowmask = (1 << p) - 1;
    const int cv = 1 - inv, tv = inv;
    const int lofs = lane * 8;          // element offset of this lane's frag

    // ---- GEMM1 B-frags: X^T = [z_cond | c | 0pad], one per row-tile ----
    Frag bx[4];
    #pragma unroll
    for (int rt = 0; rt < 4; ++rt) {
        const int n = rt * 16 + l15;
        const float* zr = z + (size_t)(row0 + n) * DIN;
        const float* cr = c + (size_t)(row0 + n) * DC;
        float v[8];
        if (quad == 0) {
            #pragma unroll
            for (int j = 0; j < 8; ++j) {
                const int col = ((j >> p) << (p + 1)) | (cv << p) | (j & lowmask);
                v[j] = zr[col];
            }
        } else if (quad == 1) {
            #pragma unroll
            for (int j = 0; j < 8; ++j) v[j] = cr[j];
        } else if (quad == 2) {
            #pragma unroll
            for (int j = 0; j < 8; ++j) v[j] = cr[8 + j];
        } else {
            #pragma unroll
            for (int j = 0; j < 8; ++j) v[j] = 0.f;
        }
        #pragma unroll
        for (int j = 0; j < 4; ++j) bx[rt].u32[j] = pack2h(v[2 * j], v[2 * j + 1]);
    }

    // ---- GEMM1: H0^T = relu(W0F @ X^T + b0) -> swizzled LDS ----
    #pragma unroll
    for (int j = 0; j < 4; ++j) {
        const int ut = wave * 4 + j;
        Frag a; a.q = *(const uint4*)(W0F + (ut << 9) + lofs);
        const f32x4 bias = *(const f32x4*)(b0 + ut * 16 + quad * 4);
        const int m0 = ut * 16 + quad * 4;
        #pragma unroll
        for (int rt = 0; rt < 4; ++rt) {
            f32x4 acc = __builtin_amdgcn_mfma_f32_16x16x32_f16(a.v, bx[rt].v, bias, 0, 0, 0);
            const int n = rt * 16 + l15;
            uint2 w2;
            w2.x = pack2h(fmaxf(acc.x, 0.f), fmaxf(acc.y, 0.f));
            w2.y = pack2h(fmaxf(acc.z, 0.f), fmaxf(acc.w, 0.f));
            const int addr = n * 1024 + (((m0 >> 3) ^ (n & 7)) * 16) + ((m0 & 4) * 2);
            *(uint2*)(smem + addr) = w2;
        }
    }
    __syncthreads();

    // ---- GEMM2: H1 = relu(H0 @ W1 + b1), kept in registers ----
    f32x4 h1[4][4];   // [j][rt]
    #pragma unroll
    for (int j = 0; j < 4; ++j) {
        const int ut = wave * 4 + j;
        const f32x4 bias = *(const f32x4*)(b1 + ut * 16 + quad * 4);
        #pragma unroll
        for (int rt = 0; rt < 4; ++rt) h1[j][rt] = bias;
    }
    #pragma unroll 4
    for (int ks = 0; ks < 16; ++ks) {
        Frag B[4];
        #pragma unroll
        for (int rt = 0; rt < 4; ++rt) {
            const int n = rt * 16 + l15;
            B[rt].v = *(const h16x8*)(smem + n * 1024 + (((ks * 4 + quad) ^ (n & 7)) * 16));
        }
        __builtin_amdgcn_s_setprio(1);
        #pragma unroll
        for (int j = 0; j < 4; ++j) {
            const int ut = wave * 4 + j;
            Frag a; a.q = *(const uint4*)(W1F + (((ut << 4) + ks) << 9) + lofs);
            #pragma unroll
            for (int rt = 0; rt < 4; ++rt)
                h1[j][rt] = __builtin_amdgcn_mfma_f32_16x16x32_f16(a.v, B[rt].v, h1[j][rt], 0, 0, 0);
        }
        __builtin_amdgcn_s_setprio(0);
    }
    __syncthreads();   // everyone done reading H0

    // ---- stage full H1 (relu, fp16) into the same 64 KB swizzled LDS ----
    #pragma unroll
    for (int j = 0; j < 4; ++j) {
        const int ut = wave * 4 + j;
        const int m0 = ut * 16 + quad * 4;
        #pragma unroll
        for (int rt = 0; rt < 4; ++rt) {
            const int n = rt * 16 + l15;
            uint2 w2;
            w2.x = pack2h(fmaxf(h1[j][rt].x, 0.f), fmaxf(h1[j][rt].y, 0.f));
            w2.y = pack2h(fmaxf(h1[j][rt].z, 0.f), fmaxf(h1[j][rt].w, 0.f));
            const int addr = n * 1024 + (((m0 >> 3) ^ (n & 7)) * 16) + ((m0 & 4) * 2);
            *(uint2*)(smem + addr) = w2;
        }
    }
    __syncthreads();

    // ---- GEMM3: P = H1 @ W2 + b2, barrier-free K-stream ----
    f32x4 pacc[2][4];
    #pragma unroll
    for (int i2 = 0; i2 < 2; ++i2) {
        const int m0 = (wave * 2 + i2) * 16 + quad * 4;
        f32x4 bias;
        if (m0 < FOUT) bias = *(const f32x4*)(b2 + m0);
        else { bias.x = 0.f; bias.y = 0.f; bias.z = 0.f; bias.w = 0.f; }
        #pragma unroll
        for (int rt = 0; rt < 4; ++rt) pacc[i2][rt] = bias;
    }
    #pragma unroll 4
    for (int kk = 0; kk < 16; ++kk) {      // kk = c2*4 + ks2
        const int kc = kk * 4 + quad;      // chunk index 0..63
        Frag B[4];
        #pragma unroll
        for (int rt = 0; rt < 4; ++rt) {
            const int n = rt * 16 + l15;
            B[rt].v = *(const h16x8*)(smem + n * 1024 + ((kc ^ (n & 7)) * 16));
        }
        __builtin_amdgcn_s_setprio(1);
        #pragma unroll
        for (int i2 = 0; i2 < 2; ++i2) {
            const int ut2 = wave * 2 + i2;
            Frag a; a.q = *(const uint4*)(W2F + (((ut2 << 4) + kk) << 9) + lofs);
            #pragma unroll
            for (int rt = 0; rt < 4; ++rt)
                pacc[i2][rt] = __builtin_amdgcn_mfma_f32_16x16x32_f16(a.v, B[rt].v, pacc[i2][rt], 0, 0, 0);
        }
        __builtin_amdgcn_s_setprio(0);
    }
    __syncthreads();   // H1 reads done; reuse LDS for fp32 P

    // ---- dump P (fp32) to LDS for the spline phase: [64 rows][252] ----
    #pragma unroll
    for (int i2 = 0; i2 < 2; ++i2) {
        const int m0 = (wave * 2 + i2) * 16 + quad * 4;
        if (m0 < FOUT) {
            #pragma unroll
            for (int rt = 0; rt < 4; ++rt) {
                const int n = rt * 16 + l15;
                *(f32x4*)(smem + n * 1008 + m0 * 4) = pacc[i2][rt];
            }
        }
    }
    __syncthreads();

    // ---- RQS spline: thread t -> (row r = t>>3, dim d = t&7) ----
    // Native transcendentals; fused logdet log; cndmask bin-select; lazy softplus
    // (select raw uk, uk1 first, softplus only those 2 — was 22 transcendentals).
    {
        const int r = t >> 3;
        const int d = t & 7;
        const int row = row0 + r;
        const int td = ((d >> p) << (p + 1)) | (tv << p) | (d & lowmask);

        // issue the scattered x load early to hide latency under the LDS reads
        const float x = z[(size_t)row * DIN + td];

        const float* pp = (const float*)(smem + r * 1008) + d * 31;
        float pv[31];
        #pragma unroll
        for (int i = 0; i < 31; ++i) pv[i] = pp[i];

        float mw = pv[0];
        #pragma unroll
        for (int i = 1; i < BINS; ++i) mw = fmaxf(mw, pv[i]);
        float w[BINS]; float sw = 0.f;
        #pragma unroll
        for (int i = 0; i < BINS; ++i) { w[i] = __expf(pv[i] - mw); sw += w[i]; }
        const float rw = (1.0f - 0.001f * BINS) * fast_rcp(sw);
        #pragma unroll
        for (int i = 0; i < BINS; ++i) w[i] = 0.001f + rw * w[i];

        float mh = pv[BINS];
        #pragma unroll
        for (int i = 1; i < BINS; ++i) mh = fmaxf(mh, pv[BINS + i]);
        float hh[BINS]; float sh = 0.f;
        #pragma unroll
        for (int i = 0; i < BINS; ++i) { hh[i] = __expf(pv[BINS + i] - mh); sh += hh[i]; }
        const float rh = (1.0f - 0.001f * BINS) * fast_rcp(sh);
        #pragma unroll
        for (int i = 0; i < BINS; ++i) hh[i] = 0.001f + rh * hh[i];

        float cw[BINS], ch[BINS];
        cw[0] = 0.f; ch[0] = 0.f;
        #pragma unroll
        for (int i = 0; i < BINS - 1; ++i) { cw[i + 1] = cw[i] + w[i]; ch[i + 1] = ch[i] + hh[i]; }

        // bin select: largest i in [0, BINS-1] with x >= cw[i]
        // (selects RAW derivative params uk, uk1; softplus applied after)
        float xk = cw[0], wk = w[0], yk = ch[0], hk = hh[0];
        float uk = pv[2 * BINS], uk1 = pv[2 * BINS + 1];
        #pragma unroll
        for (int i = 1; i < BINS; ++i) {
            const bool sel = (x >= cw[i]);
            xk  = sel ? cw[i]            : xk;
            wk  = sel ? w[i]             : wk;
            yk  = sel ? ch[i]            : yk;
            hk  = sel ? hh[i]            : hk;
            uk  = sel ? pv[2 * BINS + i]     : uk;
            uk1 = sel ? pv[2 * BINS + i + 1] : uk1;
        }
        const float dk  = 0.001f + fmaxf(uk, 0.f)  + __logf(1.f + __expf(-fabsf(uk)));
        const float dk1 = 0.001f + fmaxf(uk1, 0.f) + __logf(1.f + __expf(-fabsf(uk1)));

        const float inv_wk = fast_rcp(wk);
        float th = (x - xk) * inv_wk;
        th = fminf(fmaxf(th, 0.f), 1.f);
        const float s   = hk * inv_wk;
        const float t1  = th * (1.f - th);
        const float den = s + (dk1 + dk - 2.f * s) * t1;
        const float inv_den = fast_rcp(den);
        const float num = s * th * th + dk * t1;
        const float y   = yk + hk * num * inv_den;
        const float om  = 1.f - th;
        const float r1  = s * inv_den;                 // bounded: s/den <= ~2
        const float q   = r1 * r1 * (dk1 * th * th + 2.f * s * t1 + dk * om * om);
        float ljv = __logf(q);                          // == 2log(s)+log(num2)-2log(den)

        zout[(size_t)row * DIN + td] = y;

        float v = ljv;
        v += __shfl_down(v, 4, 8);
        v += __shfl_down(v, 2, 8);
        v += __shfl_down(v, 1, 8);
        if ((t & 7) == 0) logdet[row0 + (t >> 3)] += v;
    }
}

extern "C" void kernel_launch(void* const* d_in, const int* in_sizes, int n_in,
                              void* d_out, int out_size, void* d_ws, size_t ws_size,
                              hipStream_t stream) {
    (void)in_sizes; (void)n_in; (void)out_size; (void)ws_size;
    const float* x  = (const float*)d_in[0];
    const float* c  = (const float*)d_in[1];
    const float* W0 = (const float*)d_in[2];
    const float* b0 = (const float*)d_in[3];
    const float* W1 = (const float*)d_in[4];
    const float* b1 = (const float*)d_in[5];
    const float* W2 = (const float*)d_in[6];
    const float* b2 = (const float*)d_in[7];
    float* out = (float*)d_out;

    char* ws = (char*)d_ws;
    float* z = (float*)(ws + Z_OFF);
    _Float16* W0F = (_Float16*)(ws + W0F_OFF);
    _Float16* W1F = (_Float16*)(ws + W1F_OFF);
    _Float16* W2F = (_Float16*)(ws + W2F_OFF);

    hipMemcpyAsync(z, x, (size_t)NROWS * DIN * sizeof(float),
                   hipMemcpyDeviceToDevice, stream);
    hipMemsetAsync(out, 0, (size_t)NROWS * sizeof(float), stream);

    prep_weights<<<12800, 256, 0, stream>>>(W0, W1, W2, W0F, W1F, W2F);

    dim3 grid(NWG), block(512);
    for (int b = 0; b < 8; ++b) {
        const int p = b >> 1, inv = b & 1;
        flow_block_kernel<<<grid, block, 0, stream>>>(
            z, c,
            W0F + (size_t)b * 32 * 512,          b0 + (size_t)b * UNITS,
            W1F + (size_t)b * 32 * 16 * 512,     b1 + (size_t)b * UNITS,
            W2F + (size_t)b * 16 * 4 * 4 * 512,  b2 + (size_t)b * FOUT,
            z, out, p, inv);
    }
}